// Round 1
// baseline (324.381 us; speedup 1.0000x reference)
//
#include <hip/hip_runtime.h>

#define N_L 100000
#define N_V 1000
#define D_IN 64
#define HCH 64
#define D_OUT 32
#define E_LL 1000000

// ---- deg[c] += 1 over all ll-edges -------------------------------------
__global__ void deg_kernel(const int* __restrict__ col,
                           float* __restrict__ deg, int E) {
    int i = blockIdx.x * blockDim.x + threadIdx.x;
    int stride = gridDim.x * blockDim.x;
    for (; i < E; i += stride)
        atomicAdd(&deg[col[i]], 1.0f);
}

// ---- deg -> dinv in place ----------------------------------------------
__global__ void dinv_kernel(float* __restrict__ deg, int n) {
    int i = blockIdx.x * blockDim.x + threadIdx.x;
    if (i < n) {
        float d = deg[i];
        deg[i] = (d > 0.0f) ? rsqrtf(d) : 0.0f;
    }
}

// ---- acc[c,:] += x[r,:] * (dinv[r]*dinv[c])  (one edge per 64-lane wave)
__global__ void scatter_kernel(const float* __restrict__ x,
                               const int* __restrict__ row,
                               const int* __restrict__ col,
                               const float* __restrict__ dinv,
                               float* __restrict__ acc, int E) {
    int lane = threadIdx.x & 63;
    int group = (blockIdx.x * blockDim.x + threadIdx.x) >> 6;
    int ngroups = (gridDim.x * blockDim.x) >> 6;
    for (int e = group; e < E; e += ngroups) {
        int r = row[e];
        int c = col[e];
        float nrm = dinv[r] * dinv[c];
        float v = x[r * D_IN + lane] * nrm;
        atomicAdd(&acc[c * D_IN + lane], v);
    }
}

// ---- out = relu(acc @ Wg + bg) @ Wl + bl --------------------------------
__global__ __launch_bounds__(256) void epilogue_kernel(
    const float* __restrict__ acc,
    const float* __restrict__ Wg, const float* __restrict__ bg,
    const float* __restrict__ Wl, const float* __restrict__ bl,
    float* __restrict__ out, int n) {
    __shared__ float sWg[HCH][D_IN];   // sWg[k][j] = Wg[k*H + j] (k = in, j = out)
    __shared__ float sWl[HCH][D_OUT];
    __shared__ float sbg[HCH];
    __shared__ float sbl[D_OUT];
    for (int i = threadIdx.x; i < D_IN * HCH; i += blockDim.x)
        sWg[i >> 6][i & 63] = Wg[i];
    for (int i = threadIdx.x; i < HCH * D_OUT; i += blockDim.x)
        sWl[i >> 5][i & 31] = Wl[i];
    if (threadIdx.x < HCH)   sbg[threadIdx.x] = bg[threadIdx.x];
    if (threadIdx.x < D_OUT) sbl[threadIdx.x] = bl[threadIdx.x];
    __syncthreads();

    int i = blockIdx.x * blockDim.x + threadIdx.x;
    if (i >= n) return;

    const float4* ap = (const float4*)(acc + (size_t)i * D_IN);

    float t[HCH];
    #pragma unroll
    for (int j = 0; j < HCH; ++j) t[j] = sbg[j];

    #pragma unroll
    for (int k4 = 0; k4 < D_IN / 4; ++k4) {
        float4 v = ap[k4];
        float av[4] = {v.x, v.y, v.z, v.w};
        #pragma unroll
        for (int kk = 0; kk < 4; ++kk) {
            int k = 4 * k4 + kk;
            const float4* wr = (const float4*)&sWg[k][0];
            #pragma unroll
            for (int j4 = 0; j4 < HCH / 4; ++j4) {
                float4 w = wr[j4];
                t[4 * j4 + 0] += av[kk] * w.x;
                t[4 * j4 + 1] += av[kk] * w.y;
                t[4 * j4 + 2] += av[kk] * w.z;
                t[4 * j4 + 3] += av[kk] * w.w;
            }
        }
    }
    #pragma unroll
    for (int j = 0; j < HCH; ++j) t[j] = fmaxf(t[j], 0.0f);

    float o[D_OUT];
    #pragma unroll
    for (int j = 0; j < D_OUT; ++j) o[j] = sbl[j];
    #pragma unroll
    for (int k = 0; k < HCH; ++k) {
        const float4* wr = (const float4*)&sWl[k][0];
        #pragma unroll
        for (int j4 = 0; j4 < D_OUT / 4; ++j4) {
            float4 w = wr[j4];
            o[4 * j4 + 0] += t[k] * w.x;
            o[4 * j4 + 1] += t[k] * w.y;
            o[4 * j4 + 2] += t[k] * w.z;
            o[4 * j4 + 3] += t[k] * w.w;
        }
    }

    float4* op = (float4*)(out + (size_t)i * D_OUT);
    #pragma unroll
    for (int j4 = 0; j4 < D_OUT / 4; ++j4)
        op[j4] = make_float4(o[4 * j4], o[4 * j4 + 1], o[4 * j4 + 2], o[4 * j4 + 3]);
}

extern "C" void kernel_launch(void* const* d_in, const int* in_sizes, int n_in,
                              void* d_out, int out_size, void* d_ws, size_t ws_size,
                              hipStream_t stream) {
    const float* x_local = (const float*)d_in[0];
    const float* W_gcn   = (const float*)d_in[2];
    const float* b_gcn   = (const float*)d_in[3];
    const float* W_lin   = (const float*)d_in[10];
    const float* b_lin   = (const float*)d_in[11];
    const int*   edge_ll = (const int*)d_in[12];
    const int*   row = edge_ll;           // edge_ll[0, :]
    const int*   col = edge_ll + E_LL;    // edge_ll[1, :]

    float* acc = (float*)d_ws;                       // N_L * 64 floats
    float* deg = acc + (size_t)N_L * D_IN;           // N_L floats
    float* out = (float*)d_out;

    size_t zero_bytes = ((size_t)N_L * D_IN + N_L) * sizeof(float);
    hipMemsetAsync(d_ws, 0, zero_bytes, stream);

    deg_kernel<<<1024, 256, 0, stream>>>(col, deg, E_LL);
    dinv_kernel<<<(N_L + 255) / 256, 256, 0, stream>>>(deg, N_L);
    scatter_kernel<<<4096, 256, 0, stream>>>(x_local, row, col, deg, acc, E_LL);
    epilogue_kernel<<<(N_L + 255) / 256, 256, 0, stream>>>(
        acc, W_gcn, b_gcn, W_lin, b_lin, out, N_L);
}

// Round 2
// 232.801 us; speedup vs baseline: 1.3934x; 1.3934x over previous
//
#include <hip/hip_runtime.h>

#define N_L 100000
#define N_V 1000
#define D_IN 64
#define HCH 64
#define D_OUT 32
#define E_LL 1000000

#define SCAN_BLK 256
#define NB ((N_L + SCAN_BLK - 1) / SCAN_BLK)   // 391 blocks

// ---- deg_i[c] += 1 over all ll-edges (int atomics) ----------------------
__global__ void deg_kernel(const int* __restrict__ col,
                           int* __restrict__ deg, int E) {
    int i = blockIdx.x * blockDim.x + threadIdx.x;
    int stride = gridDim.x * blockDim.x;
    for (; i < E; i += stride)
        atomicAdd(&deg[col[i]], 1);
}

// ---- dinv[i] = deg>0 ? rsqrt(deg) : 0 ------------------------------------
__global__ void dinv_kernel(const int* __restrict__ deg,
                            float* __restrict__ dinv, int n) {
    int i = blockIdx.x * blockDim.x + threadIdx.x;
    if (i < n) {
        int d = deg[i];
        dinv[i] = (d > 0) ? rsqrtf((float)d) : 0.0f;
    }
}

// ---- scan stage A: per-block sums ---------------------------------------
__global__ void blocksum_kernel(const int* __restrict__ deg,
                                int* __restrict__ bsum) {
    __shared__ int sh[SCAN_BLK];
    int i = blockIdx.x * SCAN_BLK + threadIdx.x;
    sh[threadIdx.x] = (i < N_L) ? deg[i] : 0;
    __syncthreads();
    for (int s = SCAN_BLK / 2; s > 0; s >>= 1) {
        if (threadIdx.x < s) sh[threadIdx.x] += sh[threadIdx.x + s];
        __syncthreads();
    }
    if (threadIdx.x == 0) bsum[blockIdx.x] = sh[0];
}

// ---- scan stage B: exclusive scan of block sums (single block) ----------
__global__ void scan_bsum_kernel(const int* __restrict__ bsum,
                                 int* __restrict__ boff) {
    __shared__ int sh[512];
    int v = (threadIdx.x < NB) ? bsum[threadIdx.x] : 0;
    sh[threadIdx.x] = v;
    __syncthreads();
    for (int ofs = 1; ofs < 512; ofs <<= 1) {
        int add = (threadIdx.x >= ofs) ? sh[threadIdx.x - ofs] : 0;
        __syncthreads();
        sh[threadIdx.x] += add;
        __syncthreads();
    }
    if (threadIdx.x < NB) boff[threadIdx.x] = sh[threadIdx.x] - v;  // exclusive
}

// ---- scan stage C: per-block exclusive scan + offset -> rowptr, cursor --
__global__ void block_scan_kernel(const int* __restrict__ deg,
                                  const int* __restrict__ boff,
                                  int* __restrict__ rowptr,
                                  int* __restrict__ cursor) {
    __shared__ int sh[SCAN_BLK];
    int i = blockIdx.x * SCAN_BLK + threadIdx.x;
    int v = (i < N_L) ? deg[i] : 0;
    sh[threadIdx.x] = v;
    __syncthreads();
    for (int ofs = 1; ofs < SCAN_BLK; ofs <<= 1) {
        int add = (threadIdx.x >= ofs) ? sh[threadIdx.x - ofs] : 0;
        __syncthreads();
        sh[threadIdx.x] += add;
        __syncthreads();
    }
    if (i < N_L) {
        int excl = sh[threadIdx.x] - v + boff[blockIdx.x];
        rowptr[i] = excl;
        cursor[i] = excl;
    }
    if (i == 0) rowptr[N_L] = E_LL;
}

// ---- bucket fill: srcidx[pos] = row[e], bucketed by col[e] ---------------
__global__ void fill_kernel(const int* __restrict__ row,
                            const int* __restrict__ col,
                            int* __restrict__ cursor,
                            int* __restrict__ srcidx, int E) {
    int i = blockIdx.x * blockDim.x + threadIdx.x;
    int stride = gridDim.x * blockDim.x;
    for (; i < E; i += stride) {
        int c = col[i];
        int r = row[i];
        int pos = atomicAdd(&cursor[c], 1);
        srcidx[pos] = r;
    }
}

// ---- CSR gather: acc[c,:] = dinv[c] * sum_e x[r_e,:]*dinv[r_e] -----------
// one 64-lane wave per dst node; lane = feature channel (coalesced 256B rows)
__global__ __launch_bounds__(256) void gather_kernel(
    const float* __restrict__ x, const int* __restrict__ rowptr,
    const int* __restrict__ srcidx, const float* __restrict__ dinv,
    float* __restrict__ acc) {
    int lane = threadIdx.x & 63;
    int wid = (blockIdx.x * blockDim.x + threadIdx.x) >> 6;
    int nw = (gridDim.x * blockDim.x) >> 6;
    for (int c = wid; c < N_L; c += nw) {
        int s = rowptr[c], e = rowptr[c + 1];
        float a = 0.0f;
        int p = s;
        for (; p + 2 <= e; p += 2) {
            int r0 = srcidx[p], r1 = srcidx[p + 1];
            float v0 = x[(size_t)r0 * D_IN + lane] * dinv[r0];
            float v1 = x[(size_t)r1 * D_IN + lane] * dinv[r1];
            a += v0 + v1;
        }
        if (p < e) {
            int r = srcidx[p];
            a += x[(size_t)r * D_IN + lane] * dinv[r];
        }
        acc[(size_t)c * D_IN + lane] = a * dinv[c];
    }
}

// ---- out = relu(acc @ Wg + bg) @ Wl + bl --------------------------------
__global__ __launch_bounds__(256) void epilogue_kernel(
    const float* __restrict__ acc,
    const float* __restrict__ Wg, const float* __restrict__ bg,
    const float* __restrict__ Wl, const float* __restrict__ bl,
    float* __restrict__ out, int n) {
    __shared__ float sWg[HCH][D_IN];
    __shared__ float sWl[HCH][D_OUT];
    __shared__ float sbg[HCH];
    __shared__ float sbl[D_OUT];
    for (int i = threadIdx.x; i < D_IN * HCH; i += blockDim.x)
        sWg[i >> 6][i & 63] = Wg[i];
    for (int i = threadIdx.x; i < HCH * D_OUT; i += blockDim.x)
        sWl[i >> 5][i & 31] = Wl[i];
    if (threadIdx.x < HCH)   sbg[threadIdx.x] = bg[threadIdx.x];
    if (threadIdx.x < D_OUT) sbl[threadIdx.x] = bl[threadIdx.x];
    __syncthreads();

    int i = blockIdx.x * blockDim.x + threadIdx.x;
    if (i >= n) return;

    const float4* ap = (const float4*)(acc + (size_t)i * D_IN);

    float t[HCH];
    #pragma unroll
    for (int j = 0; j < HCH; ++j) t[j] = sbg[j];

    #pragma unroll
    for (int k4 = 0; k4 < D_IN / 4; ++k4) {
        float4 v = ap[k4];
        float av[4] = {v.x, v.y, v.z, v.w};
        #pragma unroll
        for (int kk = 0; kk < 4; ++kk) {
            int k = 4 * k4 + kk;
            const float4* wr = (const float4*)&sWg[k][0];
            #pragma unroll
            for (int j4 = 0; j4 < HCH / 4; ++j4) {
                float4 w = wr[j4];
                t[4 * j4 + 0] += av[kk] * w.x;
                t[4 * j4 + 1] += av[kk] * w.y;
                t[4 * j4 + 2] += av[kk] * w.z;
                t[4 * j4 + 3] += av[kk] * w.w;
            }
        }
    }
    #pragma unroll
    for (int j = 0; j < HCH; ++j) t[j] = fmaxf(t[j], 0.0f);

    float o[D_OUT];
    #pragma unroll
    for (int j = 0; j < D_OUT; ++j) o[j] = sbl[j];
    #pragma unroll
    for (int k = 0; k < HCH; ++k) {
        const float4* wr = (const float4*)&sWl[k][0];
        #pragma unroll
        for (int j4 = 0; j4 < D_OUT / 4; ++j4) {
            float4 w = wr[j4];
            o[4 * j4 + 0] += t[k] * w.x;
            o[4 * j4 + 1] += t[k] * w.y;
            o[4 * j4 + 2] += t[k] * w.z;
            o[4 * j4 + 3] += t[k] * w.w;
        }
    }

    float4* op = (float4*)(out + (size_t)i * D_OUT);
    #pragma unroll
    for (int j4 = 0; j4 < D_OUT / 4; ++j4)
        op[j4] = make_float4(o[4 * j4], o[4 * j4 + 1], o[4 * j4 + 2], o[4 * j4 + 3]);
}

extern "C" void kernel_launch(void* const* d_in, const int* in_sizes, int n_in,
                              void* d_out, int out_size, void* d_ws, size_t ws_size,
                              hipStream_t stream) {
    const float* x_local = (const float*)d_in[0];
    const float* W_gcn   = (const float*)d_in[2];
    const float* b_gcn   = (const float*)d_in[3];
    const float* W_lin   = (const float*)d_in[10];
    const float* b_lin   = (const float*)d_in[11];
    const int*   edge_ll = (const int*)d_in[12];
    const int*   row = edge_ll;           // edge_ll[0, :]
    const int*   col = edge_ll + E_LL;    // edge_ll[1, :]

    // workspace layout
    int*   deg_i  = (int*)d_ws;                 // N_L
    int*   rowptr = deg_i + N_L;                // N_L + 1
    int*   cursor = rowptr + N_L + 1;           // N_L
    int*   bsum   = cursor + N_L;               // 512
    int*   boff   = bsum + 512;                 // 512
    float* dinvp  = (float*)(boff + 512);       // N_L
    int*   srcidx = (int*)(dinvp + N_L);        // E_LL
    float* acc    = (float*)(srcidx + E_LL);    // N_L * D_IN
    float* out    = (float*)d_out;

    // zero only the degree counters
    hipMemsetAsync(deg_i, 0, (size_t)N_L * sizeof(int), stream);

    deg_kernel<<<1024, 256, 0, stream>>>(col, deg_i, E_LL);
    dinv_kernel<<<(N_L + 255) / 256, 256, 0, stream>>>(deg_i, dinvp, N_L);
    blocksum_kernel<<<NB, SCAN_BLK, 0, stream>>>(deg_i, bsum);
    scan_bsum_kernel<<<1, 512, 0, stream>>>(bsum, boff);
    block_scan_kernel<<<NB, SCAN_BLK, 0, stream>>>(deg_i, boff, rowptr, cursor);
    fill_kernel<<<1024, 256, 0, stream>>>(row, col, cursor, srcidx, E_LL);
    gather_kernel<<<2048, 256, 0, stream>>>(x_local, rowptr, srcidx, dinvp, acc);
    epilogue_kernel<<<(N_L + 255) / 256, 256, 0, stream>>>(
        acc, W_gcn, b_gcn, W_lin, b_lin, out, N_L);
}